// Round 11
// baseline (79.300 us; speedup 1.0000x reference)
//
#include <hip/hip_runtime.h>
#include <hip/hip_bf16.h>

#define TASKS 16
#define DIM 1024
#define HID 128
#define NCLS 10
#define NB 65536
#define BM 128
#define NTILES (NB / BM + TASKS) // 528 = 8 * 66

// ws layout (ints):
//  [0, 4096)            per-block histogram partials [256 blk][16 task]
//  [4096, 4112)         per-task totals
//  [4160, 4160+NB)      rowIdx grouped by task
//  [69696, ...) shorts: W1s [T][16 KT][16KB tile: [8 kslot][128 colslot][16B],
//                       colslot = col ^ kslot] (4MB), then W2t [T][16][128]
#define WS_TOT  4096
#define WS_RIDX 4160
#define WS_W1S  (WS_RIDX + NB)

typedef __attribute__((ext_vector_type(8))) short bf16x8;
typedef __attribute__((ext_vector_type(4))) float f32x4;

__device__ __forceinline__ unsigned short f2bf(float f) {
    union { __hip_bfloat16 h; unsigned short s; } u; u.h = __float2bfloat16(f); return u.s;
}

__device__ __forceinline__ void glds16(const void* gsrc, void* ldst) {
    __builtin_amdgcn_global_load_lds(
        (const __attribute__((address_space(1))) unsigned*)gsrc,
        (__attribute__((address_space(3))) unsigned*)ldst, 16, 0, 0);
}

// ---- pass 1: histogram partials + W1 -> kslot-major swizzled tiles + W2 ----
__global__ __launch_bounds__(256) void k_pre(const int* __restrict__ tid_arr,
                                             const float* __restrict__ W1,
                                             const float* __restrict__ W2,
                                             int* __restrict__ ws) {
    const int blk = blockIdx.x, tid = threadIdx.x;
    if (blk < 256) {
        __shared__ int l[TASKS];
        if (tid < TASKS) l[tid] = 0;
        __syncthreads();
        atomicAdd(&l[tid_arr[blk * 256 + tid]], 1);
        __syncthreads();
        if (tid < TASKS) ws[blk * TASKS + tid] = l[tid];
    } else if (blk < 512) {
        // unit (t, KT): 64 k x 128 h -> 16KB tile [kslot][colslot][16B], colslot=col^kslot
        const int idx = blk - 256;
        const int t = idx >> 4, KT = idx & 15;
        __shared__ float ld[64 * 132];
        const float* src = W1 + ((size_t)t * DIM + KT * 64) * HID;
        #pragma unroll
        for (int r = 0; r < 32; ++r) {
            const int fl = r * 256 + tid;
            ld[(fl >> 7) * 132 + (fl & 127)] = src[fl];
        }
        __syncthreads();
        char* dst = (char*)((short*)(ws + WS_W1S)) + ((size_t)(t * 16 + KT) << 14);
        #pragma unroll
        for (int g = 0; g < 4; ++g) {
            const int p = tid * 64 + g * 16;
            const int kslot = p >> 11, colslot = (p >> 4) & 127;
            const int col = colslot ^ kslot;
            bf16x8 v;
            #pragma unroll
            for (int j = 0; j < 8; ++j)
                v[j] = (short)f2bf(ld[(kslot * 8 + j) * 132 + col]);
            *(bf16x8*)(dst + p) = v;      // sequential 64B/thread
        }
    } else {
        const int t = blk - 512;
        short* W2t = (short*)(ws + WS_W1S) + ((size_t)TASKS * 32 * 4096);
        #pragma unroll
        for (int i = 0; i < 8; ++i) {
            const int o = i * 256 + tid, c = o >> 7, h = o & 127;
            const float v = (c < NCLS) ? W2[((size_t)t * HID + h) * NCLS + c] : 0.f;
            W2t[((size_t)t * 16 + c) * HID + h] = (short)f2bf(v);
        }
    }
}

// ---- pass 2: deterministic scatter, parallel 2-level prefix ----
__global__ __launch_bounds__(256) void k_scatter(const int* __restrict__ tid_arr,
                                                 int* __restrict__ ws) {
    __shared__ int part[256 * TASKS];
    __shared__ int sums[16 * TASKS];
    __shared__ int l[TASKS], offl[TASKS], prel[TASKS], totl[TASKS];
    const int b = blockIdx.x, tid = threadIdx.x;
    #pragma unroll
    for (int r = 0; r < 16; ++r) part[r * 256 + tid] = ws[r * 256 + tid];
    if (tid < TASKS) l[tid] = 0;
    __syncthreads();
    const int t = tid_arr[b * 256 + tid];
    const int rank = atomicAdd(&l[t], 1);
    {
        const int c = tid >> 4, tt = tid & 15;
        int s = 0;
        #pragma unroll
        for (int bb = 0; bb < 16; ++bb) s += part[(c * 16 + bb) * TASKS + tt];
        sums[c * TASKS + tt] = s;
    }
    __syncthreads();
    if (tid < TASKS) {
        const int cb = b >> 4;
        int pre = 0;
        for (int c = 0; c < cb; ++c) pre += sums[c * TASKS + tid];
        for (int bb = cb * 16; bb < b; ++bb) pre += part[bb * TASKS + tid];
        int tot = 0;
        #pragma unroll
        for (int c = 0; c < 16; ++c) tot += sums[c * TASKS + tid];
        prel[tid] = pre; totl[tid] = tot;
        if (b == 0) ws[WS_TOT + tid] = tot;
    }
    __syncthreads();
    if (tid == 0) {
        int ro = 0;
        for (int k = 0; k < TASKS; ++k) { offl[k] = ro; ro += totl[k]; }
    }
    __syncthreads();
    ws[WS_RIDX + offl[t] + prel[t] + rank] = b * 256 + tid;
}

// ---- pass 3: fused grouped GEMM, BK=64, 3-slot A-pipeline, counted vmcnt ----
__global__ __launch_bounds__(512, 4) void k_main(
    const float* __restrict__ x, const float* __restrict__ b1,
    const float* __restrict__ b2, const int* __restrict__ ws,
    float* __restrict__ out)
{
    // per buf (32KB): A [8 kslot][128 row^kslot][16B] | B [8 kslot][128 col^kslot][16B]
    // 2 bufs = 64KB; epilogue reuses buf0 as hl[128][256B]
    __shared__ __align__(16) short smem[32768];
    __shared__ int ridx[BM];

    const int* tot = ws + WS_TOT;
    const int* rowIdx = ws + WS_RIDX;
    const short* W1s = (const short*)(ws + WS_W1S);
    const short* W2t = W1s + ((size_t)TASKS * 32 * 4096);

    const int w = (blockIdx.x & 7) * (NTILES / 8) + (blockIdx.x >> 3);

    int t = -1, m = 0, gstart = 0;
    {
        int accT = 0, accO = 0;
        for (int k = 0; k < TASKS; ++k) {
            const int c = tot[k], nt = (c + BM - 1) >> 7;
            if (t < 0 && w < accT + nt) {
                t = k; gstart = accO + (w - accT) * BM;
                m = c - (w - accT) * BM; if (m > BM) m = BM;
            }
            accT += nt; accO += c;
        }
    }
    if (t < 0) return;

    const int tid = threadIdx.x;
    if (tid < BM) ridx[tid] = rowIdx[gstart + (tid < m ? tid : m - 1)];
    __syncthreads();

    const int lane = tid & 63, wv = tid >> 6;          // 8 waves
    const int lg = lane >> 4, lr = lane & 15;
    const int rh = wv & 1, cq = wv >> 1;
    const int wrow = rh * 64, wcol = cq * 32;

    // A staging: lane owns one kslot (16B bf16) of 2 rows per iter
    const int arow0 = wv * 16 + (lane >> 3);           // rows arow0, arow0+8
    const int ks8 = lane & 7;
    const float* gpA0 = x + ((size_t)ridx[arow0] << 10) + ks8 * 8;
    const float* gpA1 = x + ((size_t)ridx[arow0 + 8] << 10) + ks8 * 8;
    const unsigned wb0 = (unsigned)(ks8 * 2048 + ((arow0 ^ ks8) << 4));
    const unsigned wb1 = (unsigned)(ks8 * 2048 + (((arow0 + 8) ^ ks8) << 4));

    const char* w1sT = (const char*)W1s + ((size_t)t << 18);

    f32x4 aR[3][4];                                    // statically indexed (full unroll)
    f32x4 acc[4][2] = {};

    auto LOADA = [&](int s, int KT) {
        aR[s][0] = *(const f32x4*)(gpA0 + KT * 64);
        aR[s][1] = *(const f32x4*)(gpA0 + KT * 64 + 4);
        aR[s][2] = *(const f32x4*)(gpA1 + KT * 64);
        aR[s][3] = *(const f32x4*)(gpA1 + KT * 64 + 4);
    };
    auto WRITEA = [&](int buf, int s) {
        char* ab = (char*)smem + buf * 32768;
        bf16x8 p0, p1;
        #pragma unroll
        for (int e = 0; e < 4; ++e) { p0[e] = f2bf(aR[s][0][e]); p0[e+4] = f2bf(aR[s][1][e]); }
        #pragma unroll
        for (int e = 0; e < 4; ++e) { p1[e] = f2bf(aR[s][2][e]); p1[e+4] = f2bf(aR[s][3][e]); }
        *(bf16x8*)(ab + wb0) = p0;                     // ds_write_b128, conflict-free
        *(bf16x8*)(ab + wb1) = p1;
    };
    auto ISSUEB = [&](int buf, int KT) {
        const char* src = w1sT + ((size_t)KT << 14) + wv * 2048 + lane * 16;
        char* dst = (char*)smem + buf * 32768 + 16384 + wv * 2048;   // wave-uniform
        glds16(src, dst);
        glds16(src + 1024, dst + 1024);
    };
    auto COMPUTE = [&](int buf) {
        const char* ab = (const char*)smem + buf * 32768;
        const char* bb = ab + 16384;
        #pragma unroll
        for (int ks = 0; ks < 2; ++ks) {
            const int kslot = ks * 4 + lg;
            const int koff = kslot * 2048;
            bf16x8 af[4], bfr[2];
            #pragma unroll
            for (int rf = 0; rf < 4; ++rf)
                af[rf] = *(const bf16x8*)(ab + koff + (((wrow + rf * 16 + lr) ^ kslot) << 4));
            #pragma unroll
            for (int cf = 0; cf < 2; ++cf)
                bfr[cf] = *(const bf16x8*)(bb + koff + (((wcol + cf * 16 + lr) ^ kslot) << 4));
            #pragma unroll
            for (int rf = 0; rf < 4; ++rf)
                #pragma unroll
                for (int cf = 0; cf < 2; ++cf)
                    acc[rf][cf] = __builtin_amdgcn_mfma_f32_16x16x32_bf16(af[rf], bfr[cf], acc[rf][cf], 0, 0, 0);
        }
    };

    // prologue: buf0 = tile0; aR = {A0->consumed, A1, A2}; g0 drained
    LOADA(0, 0);
    ISSUEB(0, 0);
    LOADA(1, 1);
    WRITEA(0, 0);                  // auto-waits A0 only
    LOADA(2, 2);
    asm volatile("s_waitcnt vmcnt(8) lgkmcnt(0)" ::: "memory");   // drain g0 (leave A1,A2)
    __builtin_amdgcn_s_barrier();
    __builtin_amdgcn_sched_barrier(0);

    // steady: issue g_{kt+1}; write A_{kt+1}; load A_{kt+3}; compute kt;
    // vmcnt(4) drains through g_{kt+1}, leaves A_{kt+3} in flight across barrier.
    #pragma unroll
    for (int kt = 0; kt < 16; ++kt) {
        const int buf = kt & 1;
        ISSUEB(buf ^ 1, kt + 1 < 16 ? kt + 1 : 15);   // clamp keeps counts uniform
        WRITEA(buf ^ 1, (kt + 1) % 3);
        LOADA((kt + 3) % 3, kt + 3 < 16 ? kt + 3 : 15);
        COMPUTE(buf);
        asm volatile("s_waitcnt vmcnt(4) lgkmcnt(0)" ::: "memory");
        __builtin_amdgcn_s_barrier();
        __builtin_amdgcn_sched_barrier(0);
    }
    __syncthreads();   // full drain (junk tail loads) before LDS reuse

    // epilogue: bias + relu -> hl[128][256B] swizzled (reuses buf0)
    short* hl = smem;
    #pragma unroll
    for (int cf = 0; cf < 2; ++cf) {
        const int col = wcol + cf * 16 + lr;
        const float b1v = b1[t * HID + col];
        #pragma unroll
        for (int rf = 0; rf < 4; ++rf)
            #pragma unroll
            for (int q = 0; q < 4; ++q) {
                const int row = wrow + rf * 16 + lg * 4 + q;
                const float hv = fmaxf(acc[rf][cf][q] + b1v, 0.f);
                *(unsigned short*)((char*)hl + row * 256 +
                    (((col >> 3) ^ (row & 7)) << 4) + (col & 7) * 2) = f2bf(hv);
            }
    }
    __syncthreads();

    // GEMM2: [128 x 128] * [128 x 16]; wave wv owns rows wv*16..+15
    const int row2 = wv * 16 + lr;
    f32x4 acc2 = {};
    #pragma unroll
    for (int ks = 0; ks < 4; ++ks) {
        bf16x8 bvv = *(const bf16x8*)(W2t + (((size_t)t * 16 + lr) << 7) + ks * 32 + lg * 8);
        bf16x8 avv = *(const bf16x8*)((const char*)hl + row2 * 256 +
                         (((ks * 4 + lg) ^ (row2 & 7)) << 4));
        acc2 = __builtin_amdgcn_mfma_f32_16x16x32_bf16(avv, bvv, acc2, 0, 0, 0);
    }
    if (lr < NCLS) {
        const float b2v = b2[t * NCLS + lr];
        #pragma unroll
        for (int q = 0; q < 4; ++q) {
            const int row = wv * 16 + lg * 4 + q;
            if (row < m) out[(size_t)ridx[row] * NCLS + lr] = acc2[q] + b2v;
        }
    }
}

extern "C" void kernel_launch(void* const* d_in, const int* in_sizes, int n_in,
                              void* d_out, int out_size, void* d_ws, size_t ws_size,
                              hipStream_t stream) {
    (void)in_sizes; (void)n_in; (void)out_size; (void)ws_size;
    const float* x       = (const float*)d_in[0];
    const int*   task_id = (const int*)d_in[1];
    const float* W1      = (const float*)d_in[2];
    const float* b1      = (const float*)d_in[3];
    const float* W2      = (const float*)d_in[4];
    const float* b2      = (const float*)d_in[5];
    float* out = (float*)d_out;
    int* ws = (int*)d_ws;
    k_pre<<<528, 256, 0, stream>>>(task_id, W1, W2, ws);
    k_scatter<<<256, 256, 0, stream>>>(task_id, ws);
    k_main<<<NTILES, 512, 0, stream>>>(x, b1, b2, ws, out);
}